// Round 5
// baseline (225.468 us; speedup 1.0000x reference)
//
#include <hip/hip_runtime.h>
#include <type_traits>

// SOC scan:  SOC[b,t] = SOC_init(b) + sum_{k<=t} g[k],  g[0]=0,
//   g[t]  = (ts[t]-ts[t-1]) * f[t-1]
//   f[t]  = (c1 + c2*softplus(I*w1e0 + Te*w1e1 + b1e)) * I[t]
//   c1 = coef*(1+b2e), c2 = coef*w2e, coef = eta0/(3600*Q)
//
// R5 structure (fixes R4 post-mortem: ~63us vs 25us HBM floor):
//  - Unit-stride loads: lane i reads element base+i (16B/lane coalesced,
//    16 cache lines/instr vs R4's 64).
//  - In-wave shfl inclusive scan per 64-elem chunk; chunk carry via lane-63
//    broadcast; scanned values stay in REGISTERS (vals[32]/thread).
//  - LDS only for 4 wave totals + SOC_init (20 B). ONE barrier per block
//    (R4 had 3 + 38KB LDS; R2 had 128).
//  - Stores: coalesced scalar dword per element (values are lane-major).
//  - __launch_bounds__(256,4): VGPR cap 128 (vals 32 + prefetch 12 + temps).

static __device__ __forceinline__ float bf2f(unsigned int u) {
    union { unsigned int i; float f; } v;
    v.i = u << 16;
    return v.f;
}
static __device__ __forceinline__ unsigned short f2bf(float f) {
    union { unsigned int i; float f; } v;
    v.f = f;
    unsigned int x = v.i;
    return (unsigned short)((x + 0x7fffu + ((x >> 16) & 1u)) >> 16);  // RNE
}
static __device__ __forceinline__ float sp_fast(float x) {
    return __logf(1.f + __expf(x));   // v_exp_f32 / v_log_f32, |x| << 88
}

struct F4 { float ts, I, Te, U; };
static __device__ __forceinline__ F4 dec(ushort4 x) {
    return {bf2f(x.x), bf2f(x.y), bf2f(x.z), bf2f(x.w)};
}
static __device__ __forceinline__ F4 dec(float4 x) {
    return {x.x, x.y, x.z, x.w};
}

template <bool BF16>
static __device__ __forceinline__ float ld(const void* p, int i) {
    return BF16 ? bf2f(((const unsigned short*)p)[i]) : ((const float*)p)[i];
}

constexpr int BLOCK = 256;

// ---------------- main path: T == NC*256, register-resident scan ----------
template <bool BF16, int NC>
static __device__ void scan_reg(
    const void* __restrict__ Xv, const void* __restrict__ SCv,
    const void* __restrict__ W1i, const void* __restrict__ b1i,
    const void* __restrict__ W2i, const void* __restrict__ b2i,
    const void* __restrict__ W1e, const void* __restrict__ b1e,
    const void* __restrict__ W2e, const void* __restrict__ b2e,
    void* __restrict__ outv, float* s_wtot, float* s_init)
{
    using XVec = typename std::conditional<BF16, ushort4, float4>::type;
    constexpr int T = NC * 256;
    constexpr int SPAN = T / 4;          // elements per wave

    const int b    = blockIdx.x;
    const int tid  = threadIdx.x;
    const int lane = tid & 63;
    const int wave = tid >> 6;
    const int wavestart = wave * SPAN;

    const float Q    = ld<BF16>(SCv, b * 4 + 0);
    const float eta0 = ld<BF16>(SCv, b * 4 + 1);
    const float R    = ld<BF16>(SCv, b * 4 + 2);
    const float S3   = ld<BF16>(SCv, b * 4 + 3);
    const float w1e0 = ld<BF16>(W1e, 0);
    const float w1e1 = ld<BF16>(W1e, 1);
    const float vb1e = ld<BF16>(b1e, 0);
    const float coef = eta0 / (3600.f * Q);
    const float c2   = coef * ld<BF16>(W2e, 0);
    const float c1   = coef * (1.f + ld<BF16>(b2e, 0));

    const XVec* Xrow = (const XVec*)Xv + (size_t)b * T;

    // wave-predecessor carry (broadcast load, once per wave)
    float ts_c, f_c;
    if (wave > 0) {
        const F4 vp = dec(Xrow[wavestart - 1]);
        const float hp = sp_fast(fmaf(vp.I, w1e0, fmaf(vp.Te, w1e1, vb1e)));
        f_c  = fmaf(c2, hp, c1) * vp.I;
        ts_c = vp.ts;
    } else {
        const F4 v0 = dec(Xrow[0]);
        ts_c = v0.ts;                    // makes g[0] = (ts0-ts0)*0 = 0
        f_c  = 0.f;
        // SOC_init head (all wave-0 lanes compute uniformly, lane 0 writes)
        const float pre = fmaf(v0.I, ld<BF16>(W1i, 0),
                          fmaf(v0.Te, ld<BF16>(W1i, 1),
                          fmaf(v0.U, ld<BF16>(W1i, 2),
                          fmaf(R, ld<BF16>(W1i, 3), ld<BF16>(b1i, 0)))));
        const float h0 = sp_fast(pre);
        if (lane == 0)
            *s_init = S3 * (1.f + fmaf(h0, ld<BF16>(W2i, 0), ld<BF16>(b2i, 0)));
    }

    // ---- Phase 1: unit-stride chunks, in-wave scan, values in registers ----
    float vals[NC];
    float carry = 0.f;
    XVec cur = Xrow[wavestart + lane];
    XVec nxt = Xrow[wavestart + 64 + lane];
    #pragma unroll
    for (int c = 0; c < NC; ++c) {
        XVec after = cur;
        if (c + 2 < NC) after = Xrow[wavestart + (c + 2) * 64 + lane];

        const F4 v = dec(cur);
        const float f = fmaf(c2, sp_fast(fmaf(v.I, w1e0, fmaf(v.Te, w1e1, vb1e))), c1) * v.I;

        float pts = __shfl_up(v.ts, 1, 64);
        float pf  = __shfl_up(f,   1, 64);
        if (lane == 0) { pts = ts_c; pf = f_c; }
        float g = (v.ts - pts) * pf;

        #pragma unroll
        for (int d = 1; d < 64; d <<= 1) {   // in-wave inclusive scan
            const float u = __shfl_up(g, d, 64);
            if (lane >= d) g += u;
        }
        g += carry;
        vals[c] = g;

        carry = __shfl(g, 63, 64);           // serial carry (only true dep)
        ts_c  = __shfl(v.ts, 63, 64);
        f_c   = __shfl(f, 63, 64);
        cur = nxt; nxt = after;
    }
    if (lane == 0) s_wtot[wave] = carry;     // wave total
    __syncthreads();                         // the ONLY barrier

    float base = *s_init;
    #pragma unroll
    for (int w = 0; w < 3; ++w)
        if (w < wave) base += s_wtot[w];

    // ---- Phase 2: coalesced scalar stores (values are lane-major) ----
    if (!BF16) {
        float* op = (float*)outv + (size_t)b * T + wavestart + lane;
        #pragma unroll
        for (int c = 0; c < NC; ++c) op[c * 64] = vals[c] + base;
    } else {
        unsigned short* op = (unsigned short*)outv + (size_t)b * T + wavestart + lane;
        #pragma unroll
        for (int c = 0; c < NC; ++c) op[c * 64] = f2bf(vals[c] + base);
    }
}

__global__ __launch_bounds__(BLOCK, 4) void socnet_reg(
    const void* __restrict__ X, const void* __restrict__ SC,
    const void* __restrict__ W1i, const void* __restrict__ b1i,
    const void* __restrict__ W2i, const void* __restrict__ b2i,
    const void* __restrict__ W1e, const void* __restrict__ b1e,
    const void* __restrict__ W2e, const void* __restrict__ b2e,
    void* __restrict__ out)
{
    __shared__ float s_wtot[4];
    __shared__ float s_init;

    // dtype detection from SC (uniform [0.5,1.5]); resolved f32 in round 2
    const unsigned int* scw = (const unsigned int*)SC;
    const float l0 = bf2f(scw[0] & 0xFFFFu), l1 = bf2f(scw[1] & 0xFFFFu);
    const float l2 = bf2f(scw[2] & 0xFFFFu), l3 = bf2f(scw[3] & 0xFFFFu);
    const bool isbf =
        (l0 >= 0.45f && l0 <= 1.55f) && (l1 >= 0.45f && l1 <= 1.55f) &&
        (l2 >= 0.45f && l2 <= 1.55f) && (l3 >= 0.45f && l3 <= 1.55f);

    if (isbf) scan_reg<true, 32>(X, SC, W1i, b1i, W2i, b2i, W1e, b1e, W2e, b2e,
                                 out, s_wtot, &s_init);
    else      scan_reg<false, 32>(X, SC, W1i, b1i, W2i, b2i, W1e, b1e, W2e, b2e,
                                  out, s_wtot, &s_init);
}

// ---------------- fallback (T != 8192): R2-style serial-carry, correct ----
template <bool BF16>
static __device__ void scan_serial(
    const void* __restrict__ Xv, const void* __restrict__ SCv,
    const void* __restrict__ W1i, const void* __restrict__ b1i,
    const void* __restrict__ W2i, const void* __restrict__ b2i,
    const void* __restrict__ W1e, const void* __restrict__ b1e,
    const void* __restrict__ W2e, const void* __restrict__ b2e,
    void* __restrict__ outv, int T,
    float* s_wts, float* s_wf, float* s_wsum, float* s_carr)
{
    using XVec = typename std::conditional<BF16, ushort4, float4>::type;
    const int b = blockIdx.x, tid = threadIdx.x;
    const int lane = tid & 63, wave = tid >> 6;
    const int ntile = (T + BLOCK - 1) / BLOCK;

    const float Q    = ld<BF16>(SCv, b * 4 + 0);
    const float eta0 = ld<BF16>(SCv, b * 4 + 1);
    const float R    = ld<BF16>(SCv, b * 4 + 2);
    const float S3   = ld<BF16>(SCv, b * 4 + 3);
    const float w1e0 = ld<BF16>(W1e, 0);
    const float w1e1 = ld<BF16>(W1e, 1);
    const float vb1e = ld<BF16>(b1e, 0);
    const float coef = eta0 / (3600.f * Q);
    const float c2   = coef * ld<BF16>(W2e, 0);
    const float c1   = coef * (1.f + ld<BF16>(b2e, 0));

    const XVec* Xrow = (const XVec*)Xv + (size_t)b * T;

    for (int tile = 0; tile < ntile; ++tile) {
        const int t = tile * BLOCK + tid;
        const bool act = t < T;
        F4 v = {0.f, 0.f, 0.f, 0.f};
        if (act) v = dec(Xrow[t]);
        const float f = fmaf(c2, sp_fast(fmaf(v.I, w1e0, fmaf(v.Te, w1e1, vb1e))), c1) * v.I;

        float pts = __shfl_up(v.ts, 1, 64);
        float pf  = __shfl_up(f, 1, 64);

        __syncthreads();
        if (lane == 63) { s_wts[wave] = v.ts; s_wf[wave] = f; }
        if (tile == 0 && tid == 0) {
            const float pre = fmaf(v.I, ld<BF16>(W1i, 0),
                              fmaf(v.Te, ld<BF16>(W1i, 1),
                              fmaf(v.U, ld<BF16>(W1i, 2),
                              fmaf(R, ld<BF16>(W1i, 3), ld<BF16>(b1i, 0)))));
            s_carr[0] = S3 * (1.f + fmaf(sp_fast(pre), ld<BF16>(W2i, 0), ld<BF16>(b2i, 0)));
        }
        __syncthreads();
        if (lane == 0) {
            if (wave == 0) { if (tile > 0) { pts = s_carr[1]; pf = s_carr[2]; } }
            else { pts = s_wts[wave - 1]; pf = s_wf[wave - 1]; }
        }
        float g = (t == 0 || !act) ? 0.f : (v.ts - pts) * pf;
        #pragma unroll
        for (int d = 1; d < 64; d <<= 1) {
            const float u = __shfl_up(g, d, 64);
            if (lane >= d) g += u;
        }
        if (lane == 63) s_wsum[wave] = g;
        __syncthreads();
        float soc = s_carr[0];
        #pragma unroll
        for (int w = 0; w < 3; ++w) if (w < wave) soc += s_wsum[w];
        soc += g;
        if (act) {
            if (BF16) ((unsigned short*)outv)[(size_t)b * T + t] = f2bf(soc);
            else      ((float*)outv)[(size_t)b * T + t] = soc;
        }
        __syncthreads();
        if (tid == BLOCK - 1) { s_carr[0] = soc; s_carr[1] = v.ts; s_carr[2] = f; }
    }
}

__global__ __launch_bounds__(BLOCK) void socnet_serial_k(
    const void* __restrict__ X, const void* __restrict__ SC,
    const void* __restrict__ W1i, const void* __restrict__ b1i,
    const void* __restrict__ W2i, const void* __restrict__ b2i,
    const void* __restrict__ W1e, const void* __restrict__ b1e,
    const void* __restrict__ W2e, const void* __restrict__ b2e,
    void* __restrict__ out, int T)
{
    __shared__ float s_wts[4], s_wf[4], s_wsum[4], s_carr[3];
    const unsigned int* scw = (const unsigned int*)SC;
    const float l0 = bf2f(scw[0] & 0xFFFFu), l1 = bf2f(scw[1] & 0xFFFFu);
    const float l2 = bf2f(scw[2] & 0xFFFFu), l3 = bf2f(scw[3] & 0xFFFFu);
    const bool isbf =
        (l0 >= 0.45f && l0 <= 1.55f) && (l1 >= 0.45f && l1 <= 1.55f) &&
        (l2 >= 0.45f && l2 <= 1.55f) && (l3 >= 0.45f && l3 <= 1.55f);
    if (isbf) scan_serial<true >(X, SC, W1i, b1i, W2i, b2i, W1e, b1e, W2e, b2e,
                                 out, T, s_wts, s_wf, s_wsum, s_carr);
    else      scan_serial<false>(X, SC, W1i, b1i, W2i, b2i, W1e, b1e, W2e, b2e,
                                 out, T, s_wts, s_wf, s_wsum, s_carr);
}

extern "C" void kernel_launch(void* const* d_in, const int* in_sizes, int n_in,
                              void* d_out, int out_size, void* d_ws, size_t ws_size,
                              hipStream_t stream) {
    const int B = in_sizes[1] / 4;        // 1024
    const int T = in_sizes[0] / (B * 4);  // 8192

    if (T == 8192) {
        socnet_reg<<<dim3(B), dim3(BLOCK), 0, stream>>>(
            d_in[0], d_in[1], d_in[2], d_in[3], d_in[4], d_in[5],
            d_in[6], d_in[7], d_in[8], d_in[9], d_out);
    } else {
        socnet_serial_k<<<dim3(B), dim3(BLOCK), 0, stream>>>(
            d_in[0], d_in[1], d_in[2], d_in[3], d_in[4], d_in[5],
            d_in[6], d_in[7], d_in[8], d_in[9], d_out, T);
    }
}

// Round 6
// 219.942 us; speedup vs baseline: 1.0251x; 1.0251x over previous
//
#include <hip/hip_runtime.h>
#include <type_traits>

// SOC scan:  SOC[b,t] = SOC_init(b) + sum_{k<=t} g[k],  g[0]=0,
//   g[t]  = (ts[t]-ts[t-1]) * f[t-1]
//   f[t]  = (c1 + c2*softplus(I*w1e0 + Te*w1e1 + b1e)) * I[t]
//   c1 = coef*(1+b2e), c2 = coef*w2e, coef = eta0/(3600*Q)
//
// R6: R2/R4/R5 all hit ~61-70us (vs 25us HBM floor) -> MLP-starved latency
// bound (VGPR-capped ~2 outstanding loads/wave). Fix: global_load_lds DMA
// staging (no VGPR per outstanding load), 16KB tile in LDS, predecessor read
// straight from LDS (no shfl chains), 16 independent chunk scans per tile,
// parity-slot carry (no extra barriers). 2 barriers/tile, 4 blocks/CU.

static __device__ __forceinline__ float bf2f(unsigned int u) {
    union { unsigned int i; float f; } v;
    v.i = u << 16;
    return v.f;
}
static __device__ __forceinline__ unsigned short f2bf(float f) {
    union { unsigned int i; float f; } v;
    v.f = f;
    unsigned int x = v.i;
    return (unsigned short)((x + 0x7fffu + ((x >> 16) & 1u)) >> 16);  // RNE
}
static __device__ __forceinline__ float sp_fast(float x) {
    return __logf(1.f + __expf(x));   // v_exp_f32 / v_log_f32, |x| << 88
}

struct F4 { float ts, I, Te, U; };
static __device__ __forceinline__ F4 dec(ushort4 x) {
    return {bf2f(x.x), bf2f(x.y), bf2f(x.z), bf2f(x.w)};
}
static __device__ __forceinline__ F4 dec(float4 x) {
    return {x.x, x.y, x.z, x.w};
}

template <bool BF16>
static __device__ __forceinline__ float ld(const void* p, int i) {
    return BF16 ? bf2f(((const unsigned short*)p)[i]) : ((const float*)p)[i];
}

constexpr int BLOCK = 256;
constexpr int TT    = 1024;          // elements per staged tile (16 KB LDS)

// async global->LDS DMA, 16 B per lane; LDS dest = wave-uniform base + lane*16
static __device__ __forceinline__ void dma16(const float4* g, float4* l) {
    __builtin_amdgcn_global_load_lds(
        (const __attribute__((address_space(1))) unsigned int*)g,
        (__attribute__((address_space(3))) unsigned int*)l, 16, 0, 0);
}

// ---------------- serial-carry path (insurance: bf16 input or odd T) ------
template <bool BF16>
static __device__ void scan_serial(
    const void* __restrict__ Xv, const void* __restrict__ SCv,
    const void* __restrict__ W1i, const void* __restrict__ b1i,
    const void* __restrict__ W2i, const void* __restrict__ b2i,
    const void* __restrict__ W1e, const void* __restrict__ b1e,
    const void* __restrict__ W2e, const void* __restrict__ b2e,
    void* __restrict__ outv, int T,
    float* s_wts, float* s_wf, float* s_wsum, float* s_carr)
{
    using XVec = typename std::conditional<BF16, ushort4, float4>::type;
    const int b = blockIdx.x, tid = threadIdx.x;
    const int lane = tid & 63, wave = tid >> 6;
    const int ntile = (T + BLOCK - 1) / BLOCK;

    const float Q    = ld<BF16>(SCv, b * 4 + 0);
    const float eta0 = ld<BF16>(SCv, b * 4 + 1);
    const float R    = ld<BF16>(SCv, b * 4 + 2);
    const float S3   = ld<BF16>(SCv, b * 4 + 3);
    const float w1e0 = ld<BF16>(W1e, 0);
    const float w1e1 = ld<BF16>(W1e, 1);
    const float vb1e = ld<BF16>(b1e, 0);
    const float coef = eta0 / (3600.f * Q);
    const float c2   = coef * ld<BF16>(W2e, 0);
    const float c1   = coef * (1.f + ld<BF16>(b2e, 0));

    const XVec* Xrow = (const XVec*)Xv + (size_t)b * T;

    for (int tile = 0; tile < ntile; ++tile) {
        const int t = tile * BLOCK + tid;
        const bool act = t < T;
        F4 v = {0.f, 0.f, 0.f, 0.f};
        if (act) v = dec(Xrow[t]);
        const float f = fmaf(c2, sp_fast(fmaf(v.I, w1e0, fmaf(v.Te, w1e1, vb1e))), c1) * v.I;

        float pts = __shfl_up(v.ts, 1, 64);
        float pf  = __shfl_up(f, 1, 64);

        __syncthreads();
        if (lane == 63) { s_wts[wave] = v.ts; s_wf[wave] = f; }
        if (tile == 0 && tid == 0) {
            const float pre = fmaf(v.I, ld<BF16>(W1i, 0),
                              fmaf(v.Te, ld<BF16>(W1i, 1),
                              fmaf(v.U, ld<BF16>(W1i, 2),
                              fmaf(R, ld<BF16>(W1i, 3), ld<BF16>(b1i, 0)))));
            s_carr[0] = S3 * (1.f + fmaf(sp_fast(pre), ld<BF16>(W2i, 0), ld<BF16>(b2i, 0)));
        }
        __syncthreads();
        if (lane == 0) {
            if (wave == 0) { if (tile > 0) { pts = s_carr[1]; pf = s_carr[2]; } }
            else { pts = s_wts[wave - 1]; pf = s_wf[wave - 1]; }
        }
        float g = (t == 0 || !act) ? 0.f : (v.ts - pts) * pf;
        #pragma unroll
        for (int d = 1; d < 64; d <<= 1) {
            const float u = __shfl_up(g, d, 64);
            if (lane >= d) g += u;
        }
        if (lane == 63) s_wsum[wave] = g;
        __syncthreads();
        float soc = s_carr[0];
        #pragma unroll
        for (int w = 0; w < 3; ++w) if (w < wave) soc += s_wsum[w];
        soc += g;
        if (act) {
            if (BF16) ((unsigned short*)outv)[(size_t)b * T + t] = f2bf(soc);
            else      ((float*)outv)[(size_t)b * T + t] = soc;
        }
        __syncthreads();
        if (tid == BLOCK - 1) { s_carr[0] = soc; s_carr[1] = v.ts; s_carr[2] = f; }
    }
}

// ---------------- main path: f32, T % 1024 == 0, LDS-staged DMA -----------
__global__ __launch_bounds__(BLOCK, 4) void socnet_staged(
    const void* __restrict__ X, const void* __restrict__ SC,
    const void* __restrict__ W1i, const void* __restrict__ b1i,
    const void* __restrict__ W2i, const void* __restrict__ b2i,
    const void* __restrict__ W1e, const void* __restrict__ b1e,
    const void* __restrict__ W2e, const void* __restrict__ b2e,
    void* __restrict__ out, int T)
{
    __shared__ float4 stage[TT];                 // 16 KB staging tile
    __shared__ __align__(16) float s_tot[16];    // chunk totals
    __shared__ float s_c[2], s_pts[2], s_pf[2];  // parity carry slots
    __shared__ float s_wts[4], s_wf[4], s_wsum[4], s_carr[3];  // fallback

    // dtype detection from SC (uniform [0.5,1.5]); resolved f32 in round 2
    const unsigned int* scw = (const unsigned int*)SC;
    const float l0 = bf2f(scw[0] & 0xFFFFu), l1 = bf2f(scw[1] & 0xFFFFu);
    const float l2 = bf2f(scw[2] & 0xFFFFu), l3 = bf2f(scw[3] & 0xFFFFu);
    const bool isbf =
        (l0 >= 0.45f && l0 <= 1.55f) && (l1 >= 0.45f && l1 <= 1.55f) &&
        (l2 >= 0.45f && l2 <= 1.55f) && (l3 >= 0.45f && l3 <= 1.55f);
    if (isbf) {   // insurance only
        scan_serial<true>(X, SC, W1i, b1i, W2i, b2i, W1e, b1e, W2e, b2e,
                          out, T, s_wts, s_wf, s_wsum, s_carr);
        return;
    }

    const int b    = blockIdx.x;
    const int tid  = threadIdx.x;
    const int lane = tid & 63;
    const int w    = tid >> 6;
    const int NT   = T / TT;

    const float* SCf = (const float*)SC;
    const float Q    = SCf[b * 4 + 0];
    const float eta0 = SCf[b * 4 + 1];
    const float R    = SCf[b * 4 + 2];
    const float S3   = SCf[b * 4 + 3];
    const float w1e0 = ((const float*)W1e)[0];
    const float w1e1 = ((const float*)W1e)[1];
    const float vb1e = ((const float*)b1e)[0];
    const float coef = eta0 / (3600.f * Q);
    const float c2   = coef * ((const float*)W2e)[0];
    const float c1   = coef * (1.f + ((const float*)b2e)[0]);

    const float4* Xrow = (const float4*)X + (size_t)b * T;
    float* orow = (float*)out + (size_t)b * T;

    // preamble: SOC_init + tile0 predecessor slots (wave 0, uniform)
    if (w == 0) {
        const float4 x0 = Xrow[0];
        const float pre = fmaf(x0.y, ((const float*)W1i)[0],
                          fmaf(x0.z, ((const float*)W1i)[1],
                          fmaf(x0.w, ((const float*)W1i)[2],
                          fmaf(R, ((const float*)W1i)[3], ((const float*)b1i)[0]))));
        const float init = S3 * (1.f + fmaf(sp_fast(pre),
                             ((const float*)W2i)[0], ((const float*)b2i)[0]));
        if (lane == 0) {
            s_c[0]   = init;
            s_pts[0] = x0.x;
            s_pf[0]  = 0.f;       // makes g[0] = 0
        }
    }
    // DMA tile 0 (each wave stages its own 4 chunks, 1 KB per issue)
    {
        #pragma unroll
        for (int j = 0; j < 4; ++j) {
            const int e = (w * 4 + j) * 64 + lane;
            dma16(Xrow + e, &stage[e]);
        }
    }

    for (int t = 0; t < NT; ++t) {
        __syncthreads();                      // B1: DMA done + carry slots visible
        const int par = t & 1;
        const float cpts = s_pts[par];
        const float cpf  = s_pf[par];

        float g[4];
        float ts_last = 0.f, I_last = 0.f, Te_last = 0.f;
        #pragma unroll
        for (int j = 0; j < 4; ++j) {
            const int e = (w * 4 + j) * 64 + lane;
            const float4 v  = stage[e];
            const float4 vp = stage[e > 0 ? e - 1 : 0];
            // f of predecessor element
            float fp  = fmaf(c2, sp_fast(fmaf(vp.y, w1e0, fmaf(vp.z, w1e1, vb1e))), c1) * vp.y;
            float tsp = vp.x;
            if (e == 0) { fp = cpf; tsp = cpts; }   // cross-tile / t=0 patch
            float gg = (v.x - tsp) * fp;
            // 64-lane inclusive scan (4 independent chains, ILP)
            #pragma unroll
            for (int d = 1; d < 64; d <<= 1) {
                const float u = __shfl_up(gg, d, 64);
                if (lane >= d) gg += u;
            }
            g[j] = gg;
            if (j == 3) { ts_last = v.x; I_last = v.y; Te_last = v.z; }
        }
        #pragma unroll
        for (int j = 0; j < 4; ++j)
            if (lane == 63) s_tot[w * 4 + j] = g[j];

        __syncthreads();                      // B2: totals visible, stage free

        // issue DMA for next tile ASAP (stage reads all happened before B2)
        if (t + 1 < NT) {
            const float4* src = Xrow + (size_t)(t + 1) * TT;
            #pragma unroll
            for (int j = 0; j < 4; ++j) {
                const int e = (w * 4 + j) * 64 + lane;
                dma16(src + e, &stage[e]);
            }
        }

        const float4 q0 = *(const float4*)&s_tot[0];
        const float4 q1 = *(const float4*)&s_tot[4];
        const float4 q2 = *(const float4*)&s_tot[8];
        const float4 q3 = *(const float4*)&s_tot[12];
        float pre = s_c[par];
        if (w > 0) pre += q0.x + q0.y + q0.z + q0.w;
        if (w > 1) pre += q1.x + q1.y + q1.z + q1.w;
        if (w > 2) pre += q2.x + q2.y + q2.z + q2.w;
        const float4 mine = (w == 0) ? q0 : (w == 1) ? q1 : (w == 2) ? q2 : q3;
        const float b0 = pre;
        const float b1v = b0 + mine.x;
        const float b2v = b1v + mine.y;
        const float b3v = b2v + mine.z;

        float* op = orow + (size_t)t * TT + w * 256 + lane;
        op[0]   = g[0] + b0;
        op[64]  = g[1] + b1v;
        op[128] = g[2] + b2v;
        op[192] = g[3] + b3v;

        if (tid == BLOCK - 1) {               // update carry slots for t+1
            const int nxt = (t + 1) & 1;
            s_c[nxt]   = g[3] + b3v;          // soc of last element in tile
            s_pts[nxt] = ts_last;
            s_pf[nxt]  = fmaf(c2, sp_fast(fmaf(I_last, w1e0,
                             fmaf(Te_last, w1e1, vb1e))), c1) * I_last;
        }
    }
}

__global__ __launch_bounds__(BLOCK) void socnet_serial_k(
    const void* __restrict__ X, const void* __restrict__ SC,
    const void* __restrict__ W1i, const void* __restrict__ b1i,
    const void* __restrict__ W2i, const void* __restrict__ b2i,
    const void* __restrict__ W1e, const void* __restrict__ b1e,
    const void* __restrict__ W2e, const void* __restrict__ b2e,
    void* __restrict__ out, int T)
{
    __shared__ float s_wts[4], s_wf[4], s_wsum[4], s_carr[3];
    const unsigned int* scw = (const unsigned int*)SC;
    const float l0 = bf2f(scw[0] & 0xFFFFu), l1 = bf2f(scw[1] & 0xFFFFu);
    const float l2 = bf2f(scw[2] & 0xFFFFu), l3 = bf2f(scw[3] & 0xFFFFu);
    const bool isbf =
        (l0 >= 0.45f && l0 <= 1.55f) && (l1 >= 0.45f && l1 <= 1.55f) &&
        (l2 >= 0.45f && l2 <= 1.55f) && (l3 >= 0.45f && l3 <= 1.55f);
    if (isbf) scan_serial<true >(X, SC, W1i, b1i, W2i, b2i, W1e, b1e, W2e, b2e,
                                 out, T, s_wts, s_wf, s_wsum, s_carr);
    else      scan_serial<false>(X, SC, W1i, b1i, W2i, b2i, W1e, b1e, W2e, b2e,
                                 out, T, s_wts, s_wf, s_wsum, s_carr);
}

extern "C" void kernel_launch(void* const* d_in, const int* in_sizes, int n_in,
                              void* d_out, int out_size, void* d_ws, size_t ws_size,
                              hipStream_t stream) {
    const int B = in_sizes[1] / 4;        // 1024
    const int T = in_sizes[0] / (B * 4);  // 8192

    if (T % TT == 0) {
        socnet_staged<<<dim3(B), dim3(BLOCK), 0, stream>>>(
            d_in[0], d_in[1], d_in[2], d_in[3], d_in[4], d_in[5],
            d_in[6], d_in[7], d_in[8], d_in[9], d_out, T);
    } else {
        socnet_serial_k<<<dim3(B), dim3(BLOCK), 0, stream>>>(
            d_in[0], d_in[1], d_in[2], d_in[3], d_in[4], d_in[5],
            d_in[6], d_in[7], d_in[8], d_in[9], d_out, T);
    }
}

// Round 7
// 216.849 us; speedup vs baseline: 1.0397x; 1.0143x over previous
//
#include <hip/hip_runtime.h>
#include <type_traits>

// SOC scan:  SOC[b,t] = SOC_init(b) + sum_{k<=t} g[k],  g[0]=0,
//   g[t]  = (ts[t]-ts[t-1]) * f[t-1]
//   f[t]  = (c1 + c2*softplus(I*w1e0 + Te*w1e1 + b1e)) * I[t]
//   c1 = coef*(1+b2e), c2 = coef*w2e, coef = eta0/(3600*Q)
//
// R7: R2/R4/R5/R6 (four structures) all pinned at ~61-70us vs 25us HBM floor;
// R3 at 2 blocks/CU = exactly 2x. Diagnosis: Little's-law starvation — loaded
// HBM latency ~3-4k cy needs >=40KB in flight/CU; R5 held ~16KB, R6's DMA
// duty-cycled to ~25KB (vmcnt(0) drain at barrier, zero in flight during
// compute). Fix: depth-8 register prefetch ring on R5's one-barrier register
// scan -> ~8 KB/wave permanently outstanding = 128 KB/CU, no drain points.

static __device__ __forceinline__ float bf2f(unsigned int u) {
    union { unsigned int i; float f; } v;
    v.i = u << 16;
    return v.f;
}
static __device__ __forceinline__ unsigned short f2bf(float f) {
    union { unsigned int i; float f; } v;
    v.f = f;
    unsigned int x = v.i;
    return (unsigned short)((x + 0x7fffu + ((x >> 16) & 1u)) >> 16);  // RNE
}
static __device__ __forceinline__ float sp_fast(float x) {
    return __logf(1.f + __expf(x));   // v_exp_f32 / v_log_f32, |x| << 88
}

struct F4 { float ts, I, Te, U; };
static __device__ __forceinline__ F4 dec(ushort4 x) {
    return {bf2f(x.x), bf2f(x.y), bf2f(x.z), bf2f(x.w)};
}
static __device__ __forceinline__ F4 dec(float4 x) {
    return {x.x, x.y, x.z, x.w};
}

template <bool BF16>
static __device__ __forceinline__ float ld(const void* p, int i) {
    return BF16 ? bf2f(((const unsigned short*)p)[i]) : ((const float*)p)[i];
}

constexpr int BLOCK = 256;
constexpr int PF    = 8;       // prefetch ring depth (8 x float4 = 32 VGPR)

// ---------------- main path: f32, T == NC*256, register scan + ring -------
template <int NC>
static __device__ void scan_ring(
    const float* __restrict__ X, const float* __restrict__ SC,
    const float* __restrict__ W1i, const float* __restrict__ b1i,
    const float* __restrict__ W2i, const float* __restrict__ b2i,
    const float* __restrict__ W1e, const float* __restrict__ b1e,
    const float* __restrict__ W2e, const float* __restrict__ b2e,
    float* __restrict__ outv, float* s_wtot, float* s_init)
{
    constexpr int T = NC * 256;
    constexpr int SPAN = T / 4;

    const int b    = blockIdx.x;
    const int tid  = threadIdx.x;
    const int lane = tid & 63;
    const int wave = tid >> 6;
    const int ws   = wave * SPAN;

    const float Q    = SC[b * 4 + 0];
    const float eta0 = SC[b * 4 + 1];
    const float R    = SC[b * 4 + 2];
    const float S3   = SC[b * 4 + 3];
    const float w1e0 = W1e[0];
    const float w1e1 = W1e[1];
    const float vb1e = b1e[0];
    const float coef = eta0 / (3600.f * Q);
    const float c2   = coef * W2e[0];
    const float c1   = coef * (1.f + b2e[0]);

    const float4* Xrow = (const float4*)X + (size_t)b * T;

    // fill the ring first: 8 independent loads in flight before any use
    float4 ring[PF];
    #pragma unroll
    for (int j = 0; j < PF; ++j) ring[j] = Xrow[ws + j * 64 + lane];

    // wave-predecessor carry (one broadcast load; overlaps ring fill)
    float ts_c, f_c;
    if (wave > 0) {
        const float4 vp = Xrow[ws - 1];
        const float hp = sp_fast(fmaf(vp.y, w1e0, fmaf(vp.z, w1e1, vb1e)));
        f_c  = fmaf(c2, hp, c1) * vp.y;
        ts_c = vp.x;
    } else {
        const float4 v0 = Xrow[0];
        ts_c = v0.x;                     // makes g[0] = (ts0-ts0)*0 = 0
        f_c  = 0.f;
        const float pre = fmaf(v0.y, W1i[0],
                          fmaf(v0.z, W1i[1],
                          fmaf(v0.w, W1i[2],
                          fmaf(R, W1i[3], b1i[0]))));
        const float h0 = sp_fast(pre);
        if (lane == 0)
            *s_init = S3 * (1.f + fmaf(h0, W2i[0], b2i[0]));
    }

    float vals[NC];
    float carry = 0.f;
    #pragma unroll
    for (int c = 0; c < NC; ++c) {
        const float4 v = ring[c & (PF - 1)];
        if (c + PF < NC)                 // refill slot: keeps ~8 outstanding
            ring[c & (PF - 1)] = Xrow[ws + (c + PF) * 64 + lane];

        const float f = fmaf(c2, sp_fast(fmaf(v.y, w1e0, fmaf(v.z, w1e1, vb1e))), c1) * v.y;

        float pts = __shfl_up(v.x, 1, 64);
        float pf  = __shfl_up(f,   1, 64);
        if (lane == 0) { pts = ts_c; pf = f_c; }
        float g = (v.x - pts) * pf;

        #pragma unroll
        for (int d = 1; d < 64; d <<= 1) {   // in-wave inclusive scan
            const float u = __shfl_up(g, d, 64);
            if (lane >= d) g += u;
        }
        g += carry;
        vals[c] = g;

        carry = __shfl(g, 63, 64);           // serial carry (only true dep)
        ts_c  = __shfl(v.x, 63, 64);
        f_c   = __shfl(f, 63, 64);
    }
    if (lane == 0) s_wtot[wave] = carry;
    __syncthreads();                         // the ONLY barrier

    float base = *s_init;
    #pragma unroll
    for (int w = 0; w < 3; ++w)
        if (w < wave) base += s_wtot[w];

    float* op = outv + (size_t)b * T + ws + lane;
    #pragma unroll
    for (int c = 0; c < NC; ++c) op[c * 64] = vals[c] + base;
}

__global__ __launch_bounds__(BLOCK, 4) void socnet_reg(
    const void* __restrict__ X, const void* __restrict__ SC,
    const void* __restrict__ W1i, const void* __restrict__ b1i,
    const void* __restrict__ W2i, const void* __restrict__ b2i,
    const void* __restrict__ W1e, const void* __restrict__ b1e,
    const void* __restrict__ W2e, const void* __restrict__ b2e,
    void* __restrict__ out)
{
    __shared__ float s_wtot[4];
    __shared__ float s_init;
    scan_ring<32>((const float*)X, (const float*)SC,
                  (const float*)W1i, (const float*)b1i,
                  (const float*)W2i, (const float*)b2i,
                  (const float*)W1e, (const float*)b1e,
                  (const float*)W2e, (const float*)b2e,
                  (float*)out, s_wtot, &s_init);
}

// ---------------- fallback (bf16 input or odd T): serial-carry, correct ----
template <bool BF16>
static __device__ void scan_serial(
    const void* __restrict__ Xv, const void* __restrict__ SCv,
    const void* __restrict__ W1i, const void* __restrict__ b1i,
    const void* __restrict__ W2i, const void* __restrict__ b2i,
    const void* __restrict__ W1e, const void* __restrict__ b1e,
    const void* __restrict__ W2e, const void* __restrict__ b2e,
    void* __restrict__ outv, int T,
    float* s_wts, float* s_wf, float* s_wsum, float* s_carr)
{
    using XVec = typename std::conditional<BF16, ushort4, float4>::type;
    const int b = blockIdx.x, tid = threadIdx.x;
    const int lane = tid & 63, wave = tid >> 6;
    const int ntile = (T + BLOCK - 1) / BLOCK;

    const float Q    = ld<BF16>(SCv, b * 4 + 0);
    const float eta0 = ld<BF16>(SCv, b * 4 + 1);
    const float R    = ld<BF16>(SCv, b * 4 + 2);
    const float S3   = ld<BF16>(SCv, b * 4 + 3);
    const float w1e0 = ld<BF16>(W1e, 0);
    const float w1e1 = ld<BF16>(W1e, 1);
    const float vb1e = ld<BF16>(b1e, 0);
    const float coef = eta0 / (3600.f * Q);
    const float c2   = coef * ld<BF16>(W2e, 0);
    const float c1   = coef * (1.f + ld<BF16>(b2e, 0));

    const XVec* Xrow = (const XVec*)Xv + (size_t)b * T;

    for (int tile = 0; tile < ntile; ++tile) {
        const int t = tile * BLOCK + tid;
        const bool act = t < T;
        F4 v = {0.f, 0.f, 0.f, 0.f};
        if (act) v = dec(Xrow[t]);
        const float f = fmaf(c2, sp_fast(fmaf(v.I, w1e0, fmaf(v.Te, w1e1, vb1e))), c1) * v.I;

        float pts = __shfl_up(v.ts, 1, 64);
        float pf  = __shfl_up(f, 1, 64);

        __syncthreads();
        if (lane == 63) { s_wts[wave] = v.ts; s_wf[wave] = f; }
        if (tile == 0 && tid == 0) {
            const float pre = fmaf(v.I, ld<BF16>(W1i, 0),
                              fmaf(v.Te, ld<BF16>(W1i, 1),
                              fmaf(v.U, ld<BF16>(W1i, 2),
                              fmaf(R, ld<BF16>(W1i, 3), ld<BF16>(b1i, 0)))));
            s_carr[0] = S3 * (1.f + fmaf(sp_fast(pre), ld<BF16>(W2i, 0), ld<BF16>(b2i, 0)));
        }
        __syncthreads();
        if (lane == 0) {
            if (wave == 0) { if (tile > 0) { pts = s_carr[1]; pf = s_carr[2]; } }
            else { pts = s_wts[wave - 1]; pf = s_wf[wave - 1]; }
        }
        float g = (t == 0 || !act) ? 0.f : (v.ts - pts) * pf;
        #pragma unroll
        for (int d = 1; d < 64; d <<= 1) {
            const float u = __shfl_up(g, d, 64);
            if (lane >= d) g += u;
        }
        if (lane == 63) s_wsum[wave] = g;
        __syncthreads();
        float soc = s_carr[0];
        #pragma unroll
        for (int w = 0; w < 3; ++w) if (w < wave) soc += s_wsum[w];
        soc += g;
        if (act) {
            if (BF16) ((unsigned short*)outv)[(size_t)b * T + t] = f2bf(soc);
            else      ((float*)outv)[(size_t)b * T + t] = soc;
        }
        __syncthreads();
        if (tid == BLOCK - 1) { s_carr[0] = soc; s_carr[1] = v.ts; s_carr[2] = f; }
    }
}

__global__ __launch_bounds__(BLOCK) void socnet_serial_k(
    const void* __restrict__ X, const void* __restrict__ SC,
    const void* __restrict__ W1i, const void* __restrict__ b1i,
    const void* __restrict__ W2i, const void* __restrict__ b2i,
    const void* __restrict__ W1e, const void* __restrict__ b1e,
    const void* __restrict__ W2e, const void* __restrict__ b2e,
    void* __restrict__ out, int T)
{
    __shared__ float s_wts[4], s_wf[4], s_wsum[4], s_carr[3];
    const unsigned int* scw = (const unsigned int*)SC;
    const float l0 = bf2f(scw[0] & 0xFFFFu), l1 = bf2f(scw[1] & 0xFFFFu);
    const float l2 = bf2f(scw[2] & 0xFFFFu), l3 = bf2f(scw[3] & 0xFFFFu);
    const bool isbf =
        (l0 >= 0.45f && l0 <= 1.55f) && (l1 >= 0.45f && l1 <= 1.55f) &&
        (l2 >= 0.45f && l2 <= 1.55f) && (l3 >= 0.45f && l3 <= 1.55f);
    if (isbf) scan_serial<true >(X, SC, W1i, b1i, W2i, b2i, W1e, b1e, W2e, b2e,
                                 out, T, s_wts, s_wf, s_wsum, s_carr);
    else      scan_serial<false>(X, SC, W1i, b1i, W2i, b2i, W1e, b1e, W2e, b2e,
                                 out, T, s_wts, s_wf, s_wsum, s_carr);
}

extern "C" void kernel_launch(void* const* d_in, const int* in_sizes, int n_in,
                              void* d_out, int out_size, void* d_ws, size_t ws_size,
                              hipStream_t stream) {
    const int B = in_sizes[1] / 4;        // 1024
    const int T = in_sizes[0] / (B * 4);  // 8192

    // dtype check on host is impossible (no sync) — but round 2 resolved f32.
    // The f32 register path handles T==8192; anything else -> serial fallback
    // (which self-detects dtype on device).
    if (T == 8192) {
        socnet_reg<<<dim3(B), dim3(BLOCK), 0, stream>>>(
            d_in[0], d_in[1], d_in[2], d_in[3], d_in[4], d_in[5],
            d_in[6], d_in[7], d_in[8], d_in[9], d_out);
    } else {
        socnet_serial_k<<<dim3(B), dim3(BLOCK), 0, stream>>>(
            d_in[0], d_in[1], d_in[2], d_in[3], d_in[4], d_in[5],
            d_in[6], d_in[7], d_in[8], d_in[9], d_out, T);
    }
}